// Round 11
// baseline (481.490 us; speedup 1.0000x reference)
//
#include <hip/hip_runtime.h>
#include <hip/hip_bf16.h>
#include <hip/hip_cooperative_groups.h>

namespace cg = cooperative_groups;

typedef unsigned short ushort_t;
typedef __attribute__((ext_vector_type(8))) short short8;
typedef __attribute__((ext_vector_type(4))) float f32x4;

static __device__ inline ushort_t f2bfu(float f) {
    __hip_bfloat16 h = __float2bfloat16(f);
    ushort_t u; __builtin_memcpy(&u, &h, 2); return u;
}
static __device__ inline unsigned pkbf(float a, float b) {
    __hip_bfloat162 h2 = __float22bfloat162_rn(make_float2(a, b));
    unsigned u; __builtin_memcpy(&u, &h2, 4); return u;
}
static __device__ inline float bflo(unsigned int u) { return __uint_as_float(u << 16); }
static __device__ inline float bfhi(unsigned int u) { return __uint_as_float(u & 0xffff0000u); }

// ---------------------------------------------------------------------------
// Workspace (floats):
//   xA @0 (25600) | xB @25600 (25600) | (wT region unused) | vwT @346112 (2048)
//   pooled @348160 (32) | fbf(bf16[400][64]) @348192 (12800) |
//   W1bf(bf16[96][128]) @360992 (6144) | ptbf(bf16[21][16]) @367136 (168)
// ---------------------------------------------------------------------------

// ---------------- prep: small weight conversions (grid 16) ----------------
__global__ __launch_bounds__(256) void prep_kernel(
    const float* __restrict__ val_conv_w, const float* __restrict__ piece_table,
    const float* __restrict__ mlp_w1,
    float* __restrict__ vwT, ushort_t* __restrict__ W1bfu,
    ushort_t* __restrict__ ptbfu, float* __restrict__ pooled)
{
    int g = blockIdx.x * 256 + threadIdx.x;    // 0..4095
    for (int i = g; i < 12288; i += 4096)      // W1 bf16, rows 83..95 zero
        W1bfu[i] = (i < 83 * 128) ? f2bfu(mlp_w1[i]) : (ushort_t)0;
    if (g < 2048) vwT[g] = val_conv_w[(g & 31) * 64 + (g >> 5)];
    if (g < 336)  ptbfu[g] = f2bfu(piece_table[g]);
    if (g < 32)   pooled[g] = 0.f;
}

// ---------------- fused encoder: stem + 8 convs, cooperative --------------
// 200 blocks x 512 thr; block = 2 positions; per layer each thread holds its
// 72 conv weights (lane=oc, wave=ic-slice) in REGISTERS, loaded once.
__device__ __forceinline__ void conv2pos(
    float* acts, float* red,                   // LDS: acts[2][576], red[2][8][64]
    const float* __restrict__ in, float* __restrict__ out,
    const float* __restrict__ Wl,              // original layout [oc64][ic64][9]
    const float* __restrict__ bias, const float* __restrict__ scale,
    const float* __restrict__ offs, const float* __restrict__ resid,
    ushort_t* __restrict__ bf_out,
    const float* __restrict__ vwT, const float* __restrict__ vcb,
    float* __restrict__ pooled, int p0, int w, int lane, int tid)
{
    // weights -> registers: contiguous 72 floats at Wl + oc*576 + slice*72
    float wreg[72];
    {
        const float4* wp = (const float4*)(Wl + lane * 576 + w * 72);
        #pragma unroll
        for (int k = 0; k < 18; k++) {
            float4 t4 = wp[k];
            wreg[4 * k + 0] = t4.x; wreg[4 * k + 1] = t4.y;
            wreg[4 * k + 2] = t4.z; wreg[4 * k + 3] = t4.w;
        }
    }
    // stage both positions' 3x3 halos: [pi][9 cells][64 ch]
    if (tid < 288) {
        int pi = (tid >= 144), r = tid - pi * 144;
        int c = r >> 4, q = r & 15;
        int p = p0 + pi, y = p / 20, x = p % 20;
        int gy = y + c / 3 - 1, gx = x + c % 3 - 1;
        float4 v = make_float4(0.f, 0.f, 0.f, 0.f);
        if ((unsigned)gy < 20u && (unsigned)gx < 20u)
            v = *(const float4*)&in[(gy * 20 + gx) * 64 + q * 4];
        *(float4*)&acts[pi * 576 + c * 64 + q * 4] = v;
    }
    __syncthreads();

    #pragma unroll
    for (int pi = 0; pi < 2; pi++) {
        float a0 = 0.f, a1 = 0.f;
        #pragma unroll
        for (int t = 0; t < 9; t++) {
            float4 A0 = *(const float4*)&acts[pi * 576 + t * 64 + w * 8];
            float4 A1 = *(const float4*)&acts[pi * 576 + t * 64 + w * 8 + 4];
            a0 += A0.x * wreg[0 * 9 + t] + A0.y * wreg[1 * 9 + t];
            a1 += A0.z * wreg[2 * 9 + t] + A0.w * wreg[3 * 9 + t];
            a0 += A1.x * wreg[4 * 9 + t] + A1.y * wreg[5 * 9 + t];
            a1 += A1.z * wreg[6 * 9 + t] + A1.w * wreg[7 * 9 + t];
        }
        red[(pi * 8 + w) * 64 + lane] = a0 + a1;
    }
    __syncthreads();

    if (tid < 128) {
        int pi = tid >> 6, oc = tid & 63, p = p0 + pi;
        float tot = 0.f;
        #pragma unroll
        for (int k = 0; k < 8; k++) tot += red[(pi * 8 + k) * 64 + oc];
        float v0 = (tot + bias[oc]) * scale[oc] + offs[oc];
        if (resid) v0 += resid[p * 64 + oc];
        v0 = fmaxf(v0, 0.f);
        out[p * 64 + oc] = v0;
        if (bf_out) { bf_out[p * 64 + oc] = f2bfu(v0); acts[pi * 576 + oc] = v0; }
    }
    if (bf_out) {
        // value head: 1x1 conv 64->32 + relu + atomic pooled-sum (2 positions)
        __syncthreads();
        if (tid < 64) {
            int pi = tid >> 5, oc = tid & 31;
            float a = 0.f;
            for (int ic = 0; ic < 64; ic++)
                a += acts[pi * 576 + ic] * vwT[ic * 32 + oc];
            atomicAdd(&pooled[oc], fmaxf(a + vcb[oc], 0.f));
        }
    }
}

__global__ __launch_bounds__(512) void encoder_kernel(
    const float* __restrict__ board,
    const float* __restrict__ stem_w, const float* __restrict__ stem_b,
    const float* __restrict__ stem_s, const float* __restrict__ stem_o,
    float* __restrict__ xA, float* __restrict__ xB,
    const float* __restrict__ blk_w1, const float* __restrict__ b1,
    const float* __restrict__ s1, const float* __restrict__ o1,
    const float* __restrict__ blk_w2, const float* __restrict__ b2,
    const float* __restrict__ s2, const float* __restrict__ o2,
    ushort_t* __restrict__ fbf, const float* __restrict__ vwT,
    const float* __restrict__ vcb, float* __restrict__ pooled)
{
    cg::grid_group grid = cg::this_grid();
    __shared__ float acts[2 * 576];
    __shared__ float red[2 * 8 * 64];
    int tid = threadIdx.x;
    int w = tid >> 6, lane = tid & 63;
    int p0 = blockIdx.x * 2;

    // stem: waves 0,1 each compute one position (5->64, 3x3, bn, relu)
    if (w < 2) {
        int p = p0 + w, y = p / 20, x = p % 20;
        float acc = 0.f;
        for (int ic = 0; ic < 5; ic++) {
            #pragma unroll
            for (int t = 0; t < 9; t++) {
                int yy = y + t / 3 - 1, xx = x + t % 3 - 1;
                if ((unsigned)yy < 20u && (unsigned)xx < 20u)
                    acc += board[ic * 400 + yy * 20 + xx] * stem_w[lane * 45 + ic * 9 + t];
            }
        }
        xA[p * 64 + lane] = fmaxf((acc + stem_b[lane]) * stem_s[lane] + stem_o[lane], 0.f);
    }
    grid.sync();

    for (int l = 0; l < 4; l++) {
        conv2pos(acts, red, xA, xB, blk_w1 + l * 36864,
                 b1 + l * 64, s1 + l * 64, o1 + l * 64,
                 nullptr, nullptr, vwT, vcb, pooled, p0, w, lane, tid);
        grid.sync();
        bool last = (l == 3);
        conv2pos(acts, red, xB, xA, blk_w2 + l * 36864,
                 b2 + l * 64, s2 + l * 64, o2 + l * 64,
                 xA, last ? fbf : nullptr, vwT, vcb, pooled, p0, w, lane, tid);
        if (!last) grid.sync();
    }
}

// ---------------- policy head: MFMA GEMM, direct-to-A-frag gather ----------
// lane l gathers move m0+(l&15), channels {kq*8..+8} u {32+kq*8..+8} (kq=l>>4)
// -> the gather result IS the A-fragment; no LDS round-trip at all.
__global__ __launch_bounds__(256, 2) void policy_kernel(
    const ushort_t* __restrict__ fbf,
    const int* __restrict__ piece_id, const float* __restrict__ anchor,
    const int* __restrict__ num_cells, const float* __restrict__ size_f,
    const int* __restrict__ cells,
    const ushort_t* __restrict__ W1bfu, const ushort_t* __restrict__ ptbfu,
    const float* __restrict__ b1, const float* __restrict__ w2,
    const float* __restrict__ b2p,
    float* __restrict__ out,
    const float* __restrict__ pooled, const float* __restrict__ self_rem,
    const float* __restrict__ opp_rem, const float* __restrict__ val_w1,
    const float* __restrict__ val_b1, const float* __restrict__ val_w2,
    const float* __restrict__ val_b2)
{
    // value head MLP (block 0, first wave)
    if (blockIdx.x == 0 && threadIdx.x < 64) {
        int j = threadIdx.x;
        float acc = val_b1[j];
        for (int k = 0; k < 74; k++) {
            float vk = (k < 32) ? pooled[k] * (1.0f / 400.0f)
                                : ((k < 53) ? self_rem[k - 32] : opp_rem[k - 53]);
            acc += vk * val_w1[k * 64 + j];
        }
        float h = fmaxf(acc, 0.f);
        float prod = h * val_w2[j];
        for (int off = 32; off > 0; off >>= 1) prod += __shfl_xor(prod, off);
        if (j == 0) out[400000] = tanhf(prod + val_b2[0]);
    }

    int l  = threadIdx.x & 63, wv_ = threadIdx.x >> 6;
    int cl = l & 15, kq = l >> 4;       // A/D row group & k-quarter

    // preload W1 B-fragments: bfr[ks][nt][e] = W1bf[ks*32+kq*8+e][nt*16+cl]
    short8 bfr[3][8];
    #pragma unroll
    for (int ks = 0; ks < 3; ks++) {
        #pragma unroll
        for (int nt = 0; nt < 8; nt++) {
            short8 s;
            #pragma unroll
            for (int e = 0; e < 8; e++)
                s[e] = (short)W1bfu[(ks * 32 + kq * 8 + e) * 128 + nt * 16 + cl];
            bfr[ks][nt] = s;
        }
    }
    float b1v[8], w2v[8];
    #pragma unroll
    for (int nt = 0; nt < 8; nt++) { b1v[nt] = b1[nt * 16 + cl]; w2v[nt] = w2[nt * 16 + cl]; }
    const float b2 = b2p[0];
    const uint4* fb4 = (const uint4*)fbf;   // [400][8] uint4 rows

    int gw = blockIdx.x * 4 + wv_;          // 0..4095
    for (int m0 = gw * 16; m0 < 400000; m0 += 4096 * 16) {
        int m = m0 + cl;                    // this lane's move (4 lanes share it)
        int   pid = piece_id[m];
        int   nc  = num_cells[m];
        float2 an = ((const float2*)anchor)[m];
        float  sz = size_f[m];

        // gather-mean straight into A-fragment channels
        float g[16];
        #pragma unroll
        for (int c = 0; c < 16; c++) g[c] = 0.f;
        for (int j = 0; j < nc; j++) {
            int2 cc = ((const int2*)cells)[m * 5 + j];
            int pc = cc.y * 20 + cc.x;
            uint4 qa = fb4[pc * 8 + kq];        // channels kq*8..+7
            uint4 qb = fb4[pc * 8 + 4 + kq];    // channels 32+kq*8..+7
            g[0]  += bflo(qa.x); g[1]  += bfhi(qa.x);
            g[2]  += bflo(qa.y); g[3]  += bfhi(qa.y);
            g[4]  += bflo(qa.z); g[5]  += bfhi(qa.z);
            g[6]  += bflo(qa.w); g[7]  += bfhi(qa.w);
            g[8]  += bflo(qb.x); g[9]  += bfhi(qb.x);
            g[10] += bflo(qb.y); g[11] += bfhi(qb.y);
            g[12] += bflo(qb.z); g[13] += bfhi(qb.z);
            g[14] += bflo(qb.w); g[15] += bfhi(qb.w);
        }
        float scl = 1.0f / (float)nc;
        uint4 U0, U1, U2;
        U0.x = pkbf(g[0] * scl,  g[1] * scl);  U0.y = pkbf(g[2] * scl,  g[3] * scl);
        U0.z = pkbf(g[4] * scl,  g[5] * scl);  U0.w = pkbf(g[6] * scl,  g[7] * scl);
        U1.x = pkbf(g[8] * scl,  g[9] * scl);  U1.y = pkbf(g[10] * scl, g[11] * scl);
        U1.z = pkbf(g[12] * scl, g[13] * scl); U1.w = pkbf(g[14] * scl, g[15] * scl);
        if (kq < 2) {
            U2 = *(const uint4*)(ptbfu + pid * 16 + kq * 8);   // emb bf16 broadcast
        } else if (kq == 2) {
            U2.x = pkbf(an.x, an.y); U2.y = pkbf(sz, 0.f); U2.z = 0u; U2.w = 0u;
        } else {
            U2 = make_uint4(0u, 0u, 0u, 0u);
        }
        short8 af0, af1, af2;
        __builtin_memcpy(&af0, &U0, 16);
        __builtin_memcpy(&af1, &U1, 16);
        __builtin_memcpy(&af2, &U2, 16);

        f32x4 acc[8];
        #pragma unroll
        for (int nt = 0; nt < 8; nt++) acc[nt] = (f32x4)0.f;
        #pragma unroll
        for (int nt = 0; nt < 8; nt++) {
            acc[nt] = __builtin_amdgcn_mfma_f32_16x16x32_bf16(af0, bfr[0][nt], acc[nt], 0, 0, 0);
            acc[nt] = __builtin_amdgcn_mfma_f32_16x16x32_bf16(af1, bfr[1][nt], acc[nt], 0, 0, 0);
            acc[nt] = __builtin_amdgcn_mfma_f32_16x16x32_bf16(af2, bfr[2][nt], acc[nt], 0, 0, 0);
        }

        // epilogue: relu(h)*w2, reduce over 16 col-lanes, write 16 logits
        float p0 = 0.f, p1 = 0.f, p2 = 0.f, p3 = 0.f;
        #pragma unroll
        for (int nt = 0; nt < 8; nt++) {
            p0 += fmaxf(acc[nt].x + b1v[nt], 0.f) * w2v[nt];
            p1 += fmaxf(acc[nt].y + b1v[nt], 0.f) * w2v[nt];
            p2 += fmaxf(acc[nt].z + b1v[nt], 0.f) * w2v[nt];
            p3 += fmaxf(acc[nt].w + b1v[nt], 0.f) * w2v[nt];
        }
        #pragma unroll
        for (int off = 1; off < 16; off <<= 1) {
            p0 += __shfl_xor(p0, off); p1 += __shfl_xor(p1, off);
            p2 += __shfl_xor(p2, off); p3 += __shfl_xor(p3, off);
        }
        if (cl < 4) {
            float v = p0;
            if (cl == 1) v = p1; else if (cl == 2) v = p2; else if (cl == 3) v = p3;
            out[m0 + kq * 4 + cl] = v + b2;
        }
    }
}

// ---------------------------------------------------------------------------
extern "C" void kernel_launch(void* const* d_in, const int* in_sizes, int n_in,
                              void* d_out, int out_size, void* d_ws, size_t ws_size,
                              hipStream_t stream) {
    const float* board      = (const float*)d_in[0];
    const float* self_rem   = (const float*)d_in[1];
    const float* opp_rem    = (const float*)d_in[2];
    const int*   piece_id   = (const int*)  d_in[3];
    const float* anchor     = (const float*)d_in[4];
    const int*   num_cells  = (const int*)  d_in[5];
    const float* size_f     = (const float*)d_in[6];
    const int*   cells      = (const int*)  d_in[7];
    const float* stem_w     = (const float*)d_in[8];
    const float* stem_b     = (const float*)d_in[9];
    const float* stem_s     = (const float*)d_in[10];
    const float* stem_o     = (const float*)d_in[11];
    const float* blk_w1     = (const float*)d_in[12];
    const float* blk_b1     = (const float*)d_in[13];
    const float* blk_s1     = (const float*)d_in[14];
    const float* blk_o1     = (const float*)d_in[15];
    const float* blk_w2     = (const float*)d_in[16];
    const float* blk_b2     = (const float*)d_in[17];
    const float* blk_s2     = (const float*)d_in[18];
    const float* blk_o2     = (const float*)d_in[19];
    const float* piece_tab  = (const float*)d_in[20];
    const float* mlp_w1     = (const float*)d_in[21];
    const float* mlp_b1     = (const float*)d_in[22];
    const float* mlp_w2     = (const float*)d_in[23];
    const float* mlp_b2     = (const float*)d_in[24];
    const float* val_conv_w = (const float*)d_in[25];
    const float* val_conv_b = (const float*)d_in[26];
    const float* val_w1     = (const float*)d_in[27];
    const float* val_b1     = (const float*)d_in[28];
    const float* val_w2     = (const float*)d_in[29];
    const float* val_b2     = (const float*)d_in[30];
    float* out = (float*)d_out;

    float* ws     = (float*)d_ws;
    float* xA     = ws;
    float* xB     = ws + 25600;
    float* vwT    = ws + 346112;
    float* pooled = ws + 348160;
    ushort_t* fbf   = (ushort_t*)(ws + 348192);
    ushort_t* W1bfu = (ushort_t*)(ws + 360992);
    ushort_t* ptbfu = (ushort_t*)(ws + 367136);

    prep_kernel<<<16, 256, 0, stream>>>(
        val_conv_w, piece_tab, mlp_w1, vwT, W1bfu, ptbfu, pooled);

    void* eargs[] = {
        (void*)&board, (void*)&stem_w, (void*)&stem_b, (void*)&stem_s, (void*)&stem_o,
        (void*)&xA, (void*)&xB,
        (void*)&blk_w1, (void*)&blk_b1, (void*)&blk_s1, (void*)&blk_o1,
        (void*)&blk_w2, (void*)&blk_b2, (void*)&blk_s2, (void*)&blk_o2,
        (void*)&fbf, (void*)&vwT, (void*)&val_conv_b, (void*)&pooled
    };
    (void)hipLaunchCooperativeKernel((const void*)encoder_kernel,
                                     dim3(200), dim3(512), eargs, 0, stream);

    policy_kernel<<<1024, 256, 0, stream>>>(
        fbf, piece_id, anchor, num_cells, size_f, cells,
        W1bfu, ptbfu, mlp_b1, mlp_w2, mlp_b2, out,
        pooled, self_rem, opp_rem, val_w1, val_b1, val_w2, val_b2);
}

// Round 12
// 343.385 us; speedup vs baseline: 1.4022x; 1.4022x over previous
//
#include <hip/hip_runtime.h>
#include <hip/hip_bf16.h>

typedef unsigned short ushort_t;
typedef __attribute__((ext_vector_type(8))) short short8;
typedef __attribute__((ext_vector_type(4))) float f32x4;

static __device__ inline ushort_t f2bfu(float f) {
    __hip_bfloat16 h = __float2bfloat16(f);
    ushort_t u; __builtin_memcpy(&u, &h, 2); return u;
}
static __device__ inline unsigned pkbf(float a, float b) {
    __hip_bfloat162 h2 = __float22bfloat162_rn(make_float2(a, b));
    unsigned u; __builtin_memcpy(&u, &h2, 4); return u;
}
static __device__ inline float bflo(unsigned int u) { return __uint_as_float(u << 16); }
static __device__ inline float bfhi(unsigned int u) { return __uint_as_float(u & 0xffff0000u); }

// ---------------------------------------------------------------------------
// Workspace (floats):
//   xA @0 (25600) | xB @25600 (25600) | wT @51200 (294912) | vwT @346112 (2048)
//   pooled @348160 (32) | fbf(bf16[400][64]) @348192 (12800) |
//   W1bf(bf16[96][128]) @360992 (6144) | ptbf(bf16[21][16]) @367136 (168)
// ---------------------------------------------------------------------------

// ---------------- prep: weight transposes + misc + stem (grid 180) --------
__global__ __launch_bounds__(256) void prep_kernel(
    const float* __restrict__ board,
    const float* __restrict__ stem_w, const float* __restrict__ stem_b,
    const float* __restrict__ stem_s, const float* __restrict__ stem_o,
    float* __restrict__ xA,
    const float* __restrict__ blk_w1, const float* __restrict__ blk_w2,
    const float* __restrict__ val_conv_w, const float* __restrict__ piece_table,
    const float* __restrict__ mlp_w1,
    float* __restrict__ wT, float* __restrict__ vwT,
    ushort_t* __restrict__ W1bfu, ushort_t* __restrict__ ptbfu,
    float* __restrict__ pooled)
{
    int b = blockIdx.x, tid = threadIdx.x;
    if (b < 72) {
        // transpose one 64(oc) x 64(r2) tile of layer l: src[oc][576] -> wT[r2][64]
        __shared__ float lds[64][65];
        int l = b / 9, t9 = b % 9;
        const float* src = ((l & 1) ? blk_w2 : blk_w1) + (l >> 1) * 36864;
        int r2l = tid & 63, ocq = tid >> 6;
        #pragma unroll
        for (int pp = 0; pp < 16; pp++) {
            int oc = pp * 4 + ocq;
            lds[oc][r2l] = src[oc * 576 + t9 * 64 + r2l];
        }
        __syncthreads();
        int ocl = tid & 63, r2q = tid >> 6;
        #pragma unroll
        for (int pp = 0; pp < 16; pp++) {
            int r2 = pp * 4 + r2q;
            wT[l * 36864 + (t9 * 64 + r2) * 64 + ocl] = lds[ocl][r2];
        }
    } else if (b < 80) {
        int g = (b - 72) * 256 + tid;          // 0..2047
        for (int i = g; i < 12288; i += 2048)  // W1 bf16, rows 83..95 zero
            W1bfu[i] = (i < 83 * 128) ? f2bfu(mlp_w1[i]) : (ushort_t)0;
        if (g < 2048) vwT[g] = val_conv_w[(g & 31) * 64 + (g >> 5)];
        if (g < 336)  ptbfu[g] = f2bfu(piece_table[g]);
        if (g < 32)   pooled[g] = 0.f;
    } else {
        // stem: 5->64 conv + bn + relu, wave = 1 position
        int wv   = (b - 80) * 4 + (tid >> 6);  // 0..399
        int lane = tid & 63;
        int y = wv / 20, x = wv % 20;
        float acc = 0.f;
        for (int ic = 0; ic < 5; ic++) {
            #pragma unroll
            for (int t = 0; t < 9; t++) {
                int yy = y + t / 3 - 1, xx = x + t % 3 - 1;
                if ((unsigned)yy < 20u && (unsigned)xx < 20u)
                    acc += board[ic * 400 + yy * 20 + xx] * stem_w[lane * 45 + ic * 9 + t];
            }
        }
        xA[wv * 64 + lane] = fmaxf((acc + stem_b[lane]) * stem_s[lane] + stem_o[lane], 0.f);
    }
}

// ---------------- fused residual pair: conv1 (halo-redundant) + conv2 ------
// 200 blocks x 256 thr; block = 1x2 output tile. conv1 computed on the 3x4
// A-grid (tile + 1-halo, off-board = 0) entirely in LDS; conv2 (+residual)
// on the 2 tile positions. One launch per residual block instead of two.
__global__ __launch_bounds__(256) void conv_pair(
    const float* __restrict__ in, float* __restrict__ out,
    const float* __restrict__ wTa, const float* __restrict__ wTb,
    const float* __restrict__ ba, const float* __restrict__ sa,
    const float* __restrict__ oa,
    const float* __restrict__ bb, const float* __restrict__ sb,
    const float* __restrict__ ob,
    ushort_t* __restrict__ bf_out,             // non-null on final pair
    const float* __restrict__ vwT, const float* __restrict__ vcb,
    float* __restrict__ pooled)
{
    __shared__ float inbuf[30 * 64];           // [5 rows][6 cols][64] pair input
    __shared__ float abuf[12 * 64];            // [3 rows][4 cols][64] conv1 out
    __shared__ float red[4 * 64];              // [half][2 pos][64]
    int tid = threadIdx.x;
    int p0 = blockIdx.x * 2;
    int y0 = p0 / 20, xL = p0 % 20;            // tile = (y0,xL),(y0,xL+1)
    int w = tid >> 6, lane = tid & 63;

    // stage 5x6 input halo (rows y0-2.., cols xL-2..), zero-padded
    for (int i = tid; i < 480; i += 256) {
        int cell = i >> 4, q = i & 15;
        int r = cell / 6, c = cell - r * 6;
        int gy = y0 - 2 + r, gx = xL - 2 + c;
        float4 v = make_float4(0.f, 0.f, 0.f, 0.f);
        if ((unsigned)gy < 20u && (unsigned)gx < 20u)
            v = *(const float4*)&in[(gy * 20 + gx) * 64 + q * 4];
        *(float4*)&inbuf[cell * 64 + q * 4] = v;
    }
    __syncthreads();

    // ---- conv1 on A-grid (3x4): wave w -> A-positions 3w..3w+2, lane = oc
    {
        int pa0 = w * 3;
        int ra0 = pa0 >> 2,      ca0 = pa0 & 3;
        int ra1 = (pa0 + 1) >> 2, ca1 = (pa0 + 1) & 3;
        int ra2 = (pa0 + 2) >> 2, ca2 = (pa0 + 2) & 3;
        float a00 = 0.f, a01 = 0.f, a10 = 0.f, a11 = 0.f, a20 = 0.f, a21 = 0.f;
        #pragma unroll 3
        for (int t = 0; t < 9; t++) {
            int dy = t / 3, dx = t - dy * 3;
            const float* l0 = &inbuf[((ra0 + dy) * 6 + ca0 + dx) * 64];
            const float* l1 = &inbuf[((ra1 + dy) * 6 + ca1 + dx) * 64];
            const float* l2 = &inbuf[((ra2 + dy) * 6 + ca2 + dx) * 64];
            const float* wrow = &wTa[t * 64 + lane];
            #pragma unroll
            for (int ic4 = 0; ic4 < 16; ic4++) {
                float4 A = *(const float4*)&l0[ic4 * 4];
                float4 B = *(const float4*)&l1[ic4 * 4];
                float4 C = *(const float4*)&l2[ic4 * 4];
                float w0 = wrow[(ic4 * 4 + 0) * 576];
                float w1 = wrow[(ic4 * 4 + 1) * 576];
                float w2 = wrow[(ic4 * 4 + 2) * 576];
                float w3 = wrow[(ic4 * 4 + 3) * 576];
                a00 += A.x * w0 + A.y * w1; a01 += A.z * w2 + A.w * w3;
                a10 += B.x * w0 + B.y * w1; a11 += B.z * w2 + B.w * w3;
                a20 += C.x * w0 + C.y * w1; a21 += C.z * w2 + C.w * w3;
            }
        }
        float bv = ba[lane], sv = sa[lane], ov = oa[lane];
        {
            int y = y0 - 1 + ra0, x = xL - 1 + ca0;
            float v = ((unsigned)y < 20u && (unsigned)x < 20u)
                    ? fmaxf((a00 + a01 + bv) * sv + ov, 0.f) : 0.f;
            abuf[pa0 * 64 + lane] = v;
        }
        {
            int y = y0 - 1 + ra1, x = xL - 1 + ca1;
            float v = ((unsigned)y < 20u && (unsigned)x < 20u)
                    ? fmaxf((a10 + a11 + bv) * sv + ov, 0.f) : 0.f;
            abuf[(pa0 + 1) * 64 + lane] = v;
        }
        {
            int y = y0 - 1 + ra2, x = xL - 1 + ca2;
            float v = ((unsigned)y < 20u && (unsigned)x < 20u)
                    ? fmaxf((a20 + a21 + bv) * sv + ov, 0.f) : 0.f;
            abuf[(pa0 + 2) * 64 + lane] = v;
        }
    }
    __syncthreads();

    // ---- conv2 on the 2 tile positions: wave w -> pos w>>1, ic-half w&1
    {
        int pb = w >> 1, half = w & 1, ic0 = half * 32;
        float b0 = 0.f, b1 = 0.f;
        #pragma unroll 3
        for (int t = 0; t < 9; t++) {
            int dy = t / 3, dx = t - dy * 3;
            const float* arow = &abuf[(dy * 4 + pb + dx) * 64 + ic0];
            const float* wrow = &wTb[(ic0 * 9 + t) * 64 + lane];
            #pragma unroll
            for (int j4 = 0; j4 < 8; j4++) {
                float4 a = *(const float4*)&arow[j4 * 4];
                float w0 = wrow[(j4 * 4 + 0) * 576];
                float w1 = wrow[(j4 * 4 + 1) * 576];
                float w2 = wrow[(j4 * 4 + 2) * 576];
                float w3 = wrow[(j4 * 4 + 3) * 576];
                b0 += a.x * w0 + a.y * w1; b1 += a.z * w2 + a.w * w3;
            }
        }
        red[(half * 2 + pb) * 64 + lane] = b0 + b1;
    }
    __syncthreads();

    if (tid < 128) {
        int pb = tid >> 6, oc = tid & 63, p = p0 + pb;
        float tot = red[pb * 64 + oc] + red[(2 + pb) * 64 + oc];
        float v0 = (tot + bb[oc]) * sb[oc] + ob[oc]
                 + inbuf[(2 * 6 + 2 + pb) * 64 + oc];   // residual = pair input
        v0 = fmaxf(v0, 0.f);
        out[p * 64 + oc] = v0;
        if (bf_out) { bf_out[p * 64 + oc] = f2bfu(v0); abuf[pb * 64 + oc] = v0; }
    }
    if (bf_out) {
        // value head: 1x1 conv 64->32 + relu + atomic pooled-sum (2 positions)
        __syncthreads();
        if (tid < 64) {
            int pi = tid >> 5, oc = tid & 31;
            float a = 0.f;
            for (int ic = 0; ic < 64; ic++)
                a += abuf[pi * 64 + ic] * vwT[ic * 32 + oc];
            atomicAdd(&pooled[oc], fmaxf(a + vcb[oc], 0.f));
        }
    }
}

// ---------------- policy head: MFMA GEMM, direct-to-A-frag gather ----------
// lane l gathers move m0+(l&15), channels {kq*8..+8} u {32+kq*8..+8} (kq=l>>4)
// -> the gather result IS the A-fragment; no LDS round-trip at all.
__global__ __launch_bounds__(256, 2) void policy_kernel(
    const ushort_t* __restrict__ fbf,
    const int* __restrict__ piece_id, const float* __restrict__ anchor,
    const int* __restrict__ num_cells, const float* __restrict__ size_f,
    const int* __restrict__ cells,
    const ushort_t* __restrict__ W1bfu, const ushort_t* __restrict__ ptbfu,
    const float* __restrict__ b1, const float* __restrict__ w2,
    const float* __restrict__ b2p,
    float* __restrict__ out,
    const float* __restrict__ pooled, const float* __restrict__ self_rem,
    const float* __restrict__ opp_rem, const float* __restrict__ val_w1,
    const float* __restrict__ val_b1, const float* __restrict__ val_w2,
    const float* __restrict__ val_b2)
{
    // value head MLP (block 0, first wave)
    if (blockIdx.x == 0 && threadIdx.x < 64) {
        int j = threadIdx.x;
        float acc = val_b1[j];
        for (int k = 0; k < 74; k++) {
            float vk = (k < 32) ? pooled[k] * (1.0f / 400.0f)
                                : ((k < 53) ? self_rem[k - 32] : opp_rem[k - 53]);
            acc += vk * val_w1[k * 64 + j];
        }
        float h = fmaxf(acc, 0.f);
        float prod = h * val_w2[j];
        for (int off = 32; off > 0; off >>= 1) prod += __shfl_xor(prod, off);
        if (j == 0) out[400000] = tanhf(prod + val_b2[0]);
    }

    int l  = threadIdx.x & 63, wv_ = threadIdx.x >> 6;
    int cl = l & 15, kq = l >> 4;       // A/D row group & k-quarter

    // preload W1 B-fragments: bfr[ks][nt][e] = W1bf[ks*32+kq*8+e][nt*16+cl]
    short8 bfr[3][8];
    #pragma unroll
    for (int ks = 0; ks < 3; ks++) {
        #pragma unroll
        for (int nt = 0; nt < 8; nt++) {
            short8 s;
            #pragma unroll
            for (int e = 0; e < 8; e++)
                s[e] = (short)W1bfu[(ks * 32 + kq * 8 + e) * 128 + nt * 16 + cl];
            bfr[ks][nt] = s;
        }
    }
    float b1v[8], w2v[8];
    #pragma unroll
    for (int nt = 0; nt < 8; nt++) { b1v[nt] = b1[nt * 16 + cl]; w2v[nt] = w2[nt * 16 + cl]; }
    const float b2 = b2p[0];
    const uint4* fb4 = (const uint4*)fbf;   // [400][8] uint4 rows

    int gw = blockIdx.x * 4 + wv_;          // 0..4095
    for (int m0 = gw * 16; m0 < 400000; m0 += 4096 * 16) {
        int m = m0 + cl;                    // this lane's move (4 lanes share it)
        int   pid = piece_id[m];
        int   nc  = num_cells[m];
        float2 an = ((const float2*)anchor)[m];
        float  sz = size_f[m];

        // gather-mean straight into A-fragment channels
        float g[16];
        #pragma unroll
        for (int c = 0; c < 16; c++) g[c] = 0.f;
        for (int j = 0; j < nc; j++) {
            int2 cc = ((const int2*)cells)[m * 5 + j];
            int pc = cc.y * 20 + cc.x;
            uint4 qa = fb4[pc * 8 + kq];        // channels kq*8..+7
            uint4 qb = fb4[pc * 8 + 4 + kq];    // channels 32+kq*8..+7
            g[0]  += bflo(qa.x); g[1]  += bfhi(qa.x);
            g[2]  += bflo(qa.y); g[3]  += bfhi(qa.y);
            g[4]  += bflo(qa.z); g[5]  += bfhi(qa.z);
            g[6]  += bflo(qa.w); g[7]  += bfhi(qa.w);
            g[8]  += bflo(qb.x); g[9]  += bfhi(qb.x);
            g[10] += bflo(qb.y); g[11] += bfhi(qb.y);
            g[12] += bflo(qb.z); g[13] += bfhi(qb.z);
            g[14] += bflo(qb.w); g[15] += bfhi(qb.w);
        }
        float scl = 1.0f / (float)nc;
        uint4 U0, U1, U2;
        U0.x = pkbf(g[0] * scl,  g[1] * scl);  U0.y = pkbf(g[2] * scl,  g[3] * scl);
        U0.z = pkbf(g[4] * scl,  g[5] * scl);  U0.w = pkbf(g[6] * scl,  g[7] * scl);
        U1.x = pkbf(g[8] * scl,  g[9] * scl);  U1.y = pkbf(g[10] * scl, g[11] * scl);
        U1.z = pkbf(g[12] * scl, g[13] * scl); U1.w = pkbf(g[14] * scl, g[15] * scl);
        if (kq < 2) {
            U2 = *(const uint4*)(ptbfu + pid * 16 + kq * 8);   // emb bf16 broadcast
        } else if (kq == 2) {
            U2.x = pkbf(an.x, an.y); U2.y = pkbf(sz, 0.f); U2.z = 0u; U2.w = 0u;
        } else {
            U2 = make_uint4(0u, 0u, 0u, 0u);
        }
        short8 af0, af1, af2;
        __builtin_memcpy(&af0, &U0, 16);
        __builtin_memcpy(&af1, &U1, 16);
        __builtin_memcpy(&af2, &U2, 16);

        f32x4 acc[8];
        #pragma unroll
        for (int nt = 0; nt < 8; nt++) acc[nt] = (f32x4)0.f;
        #pragma unroll
        for (int nt = 0; nt < 8; nt++) {
            acc[nt] = __builtin_amdgcn_mfma_f32_16x16x32_bf16(af0, bfr[0][nt], acc[nt], 0, 0, 0);
            acc[nt] = __builtin_amdgcn_mfma_f32_16x16x32_bf16(af1, bfr[1][nt], acc[nt], 0, 0, 0);
            acc[nt] = __builtin_amdgcn_mfma_f32_16x16x32_bf16(af2, bfr[2][nt], acc[nt], 0, 0, 0);
        }

        // epilogue: relu(h)*w2, reduce over 16 col-lanes, write 16 logits
        float p0 = 0.f, p1 = 0.f, p2 = 0.f, p3 = 0.f;
        #pragma unroll
        for (int nt = 0; nt < 8; nt++) {
            p0 += fmaxf(acc[nt].x + b1v[nt], 0.f) * w2v[nt];
            p1 += fmaxf(acc[nt].y + b1v[nt], 0.f) * w2v[nt];
            p2 += fmaxf(acc[nt].z + b1v[nt], 0.f) * w2v[nt];
            p3 += fmaxf(acc[nt].w + b1v[nt], 0.f) * w2v[nt];
        }
        #pragma unroll
        for (int off = 1; off < 16; off <<= 1) {
            p0 += __shfl_xor(p0, off); p1 += __shfl_xor(p1, off);
            p2 += __shfl_xor(p2, off); p3 += __shfl_xor(p3, off);
        }
        if (cl < 4) {
            float v = p0;
            if (cl == 1) v = p1; else if (cl == 2) v = p2; else if (cl == 3) v = p3;
            out[m0 + kq * 4 + cl] = v + b2;
        }
    }
}

// ---------------------------------------------------------------------------
extern "C" void kernel_launch(void* const* d_in, const int* in_sizes, int n_in,
                              void* d_out, int out_size, void* d_ws, size_t ws_size,
                              hipStream_t stream) {
    const float* board      = (const float*)d_in[0];
    const float* self_rem   = (const float*)d_in[1];
    const float* opp_rem    = (const float*)d_in[2];
    const int*   piece_id   = (const int*)  d_in[3];
    const float* anchor     = (const float*)d_in[4];
    const int*   num_cells  = (const int*)  d_in[5];
    const float* size_f     = (const float*)d_in[6];
    const int*   cells      = (const int*)  d_in[7];
    const float* stem_w     = (const float*)d_in[8];
    const float* stem_b     = (const float*)d_in[9];
    const float* stem_s     = (const float*)d_in[10];
    const float* stem_o     = (const float*)d_in[11];
    const float* blk_w1     = (const float*)d_in[12];
    const float* blk_b1     = (const float*)d_in[13];
    const float* blk_s1     = (const float*)d_in[14];
    const float* blk_o1     = (const float*)d_in[15];
    const float* blk_w2     = (const float*)d_in[16];
    const float* blk_b2     = (const float*)d_in[17];
    const float* blk_s2     = (const float*)d_in[18];
    const float* blk_o2     = (const float*)d_in[19];
    const float* piece_tab  = (const float*)d_in[20];
    const float* mlp_w1     = (const float*)d_in[21];
    const float* mlp_b1     = (const float*)d_in[22];
    const float* mlp_w2     = (const float*)d_in[23];
    const float* mlp_b2     = (const float*)d_in[24];
    const float* val_conv_w = (const float*)d_in[25];
    const float* val_conv_b = (const float*)d_in[26];
    const float* val_w1     = (const float*)d_in[27];
    const float* val_b1     = (const float*)d_in[28];
    const float* val_w2     = (const float*)d_in[29];
    const float* val_b2     = (const float*)d_in[30];
    float* out = (float*)d_out;

    float* ws     = (float*)d_ws;
    float* xA     = ws;
    float* xB     = ws + 25600;
    float* wT     = ws + 51200;
    float* vwT    = ws + 346112;
    float* pooled = ws + 348160;
    ushort_t* fbf   = (ushort_t*)(ws + 348192);
    ushort_t* W1bfu = (ushort_t*)(ws + 360992);
    ushort_t* ptbfu = (ushort_t*)(ws + 367136);

    prep_kernel<<<180, 256, 0, stream>>>(
        board, stem_w, stem_b, stem_s, stem_o, xA,
        blk_w1, blk_w2, val_conv_w, piece_tab, mlp_w1,
        wT, vwT, W1bfu, ptbfu, pooled);

    const float* src = xA;
    float* dst = xB;
    for (int l = 0; l < 4; l++) {
        bool last = (l == 3);
        conv_pair<<<200, 256, 0, stream>>>(
            src, dst, wT + (2 * l) * 36864, wT + (2 * l + 1) * 36864,
            blk_b1 + l * 64, blk_s1 + l * 64, blk_o1 + l * 64,
            blk_b2 + l * 64, blk_s2 + l * 64, blk_o2 + l * 64,
            last ? fbf : nullptr, vwT, val_conv_b, pooled);
        const float* t = src; src = dst; dst = (float*)t;
    }

    policy_kernel<<<1024, 256, 0, stream>>>(
        fbf, piece_id, anchor, num_cells, size_f, cells,
        W1bfu, ptbfu, mlp_b1, mlp_w2, mlp_b2, out,
        pooled, self_rem, opp_rem, val_w1, val_b1, val_w2, val_b2);
}